// Round 3
// baseline (8557.611 us; speedup 1.0000x reference)
//
#include <hip/hip_runtime.h>
#include <hip/hip_bf16.h>
#include <cstdint>
#include <cstddef>

// SRNN: out = scan(h = tanh(xW_t + h@R)),  B=64 T=512 D_IN=512 H=1024
// phase1 GEMM xW+b -> d_out (fp32, in-place buffer for the scan), split-bf16 both operands;
// phase2 persistent kernel (plain launch, grid=256=#CUs -> co-resident by capacity),
// R resident in VGPRs (split bf16 hi/lo), per-group (8 groups x 32 WGs) atomic barrier per step.

#define Bz 64
#define Tz 512
#define Dz 512
#define Hz 1024

typedef __attribute__((ext_vector_type(8))) short s8v;      // 8 bf16 (4 VGPR) MFMA frag
typedef __attribute__((ext_vector_type(4))) float f4v;      // MFMA acc
typedef __attribute__((ext_vector_type(4))) unsigned int u4v;

__device__ __forceinline__ unsigned short f2bf(float f) {
  unsigned u = __float_as_uint(f);
  u += 0x7FFFu + ((u >> 16) & 1u);          // RNE
  return (unsigned short)(u >> 16);
}
__device__ __forceinline__ float bf2f(unsigned short h) {
  return __uint_as_float(((unsigned)h) << 16);
}
__device__ __forceinline__ void splitbf(float v, unsigned short& hi, unsigned short& lo) {
  hi = f2bf(v);
  lo = f2bf(v - bf2f(hi));
}

// ---------------- phase 0: pack W -> bf16 hi/lo in MFMA fragment order ----------------
// layout: wp[nb(8)][s(16)][mat(2: hi,lo)][colL(128)][kg(4)][jj(4)] as uint32 (bf16 pair)
__global__ void wpack_kernel(const float* __restrict__ W, unsigned int* __restrict__ wp) {
  __shared__ float wl[32 * 128];
  const int nb = blockIdx.x >> 4, s = blockIdx.x & 15;
  const int t = threadIdx.x;
#pragma unroll
  for (int i = 0; i < 16; ++i) {
    int idx = i * 256 + t;
    int kr = idx >> 7, nc = idx & 127;
    wl[idx] = W[(size_t)(s * 32 + kr) * Hz + nb * 128 + nc];
  }
  __syncthreads();
#pragma unroll
  for (int i = 0; i < 16; ++i) {
    int u = i * 256 + t;
    int jj = u & 3, kg = (u >> 2) & 3, colL = (u >> 4) & 127, mat = u >> 11;
    int k0 = kg * 8 + jj * 2;
    unsigned short h0_, l0_, h1_, l1_;
    splitbf(wl[k0 * 128 + colL], h0_, l0_);
    splitbf(wl[(k0 + 1) * 128 + colL], h1_, l1_);
    unsigned lo32 = mat ? (unsigned)l0_ : (unsigned)h0_;
    unsigned hi32 = mat ? (unsigned)l1_ : (unsigned)h1_;
    wp[(size_t)((nb * 16 + s) * 2 + mat) * 2048 + (colL * 4 + kg) * 4 + jj] =
        lo32 | (hi32 << 16);
  }
}

// ---------------- phase 1: out = x@W + b (fp32 out), both operands split bf16 ----------------
__launch_bounds__(256, 1)
__global__ void xw_kernel(const float* __restrict__ X, const unsigned int* __restrict__ wp,
                          const float* __restrict__ bias, float* __restrict__ out) {
  __shared__ f4v als[128 * 9];   // A tile fp32, 9-granule row stride + XOR swizzle (bank-safe)
  __shared__ u4v bls[1024];      // B tile, pre-packed bf16 hi/lo frags
  const int bid = blockIdx.x;
  const int mb = bid >> 3, nb = bid & 7;
  const int t = threadIdx.x;
  const int lane = t & 63, wv = t >> 6;
  const int wm = wv >> 1, wn = wv & 1;
  const int r16 = lane & 15, kg = lane >> 4;
  const int m0 = mb * 128;

  f4v acc[4][4];
#pragma unroll
  for (int i = 0; i < 4; ++i)
#pragma unroll
    for (int j = 0; j < 4; ++j) acc[i][j] = f4v{0.f, 0.f, 0.f, 0.f};

  const u4v* wp4 = (const u4v*)wp;

  for (int ks = 0; ks < 16; ++ks) {
    __syncthreads();
    // stage A (fp32, swizzled granules)
#pragma unroll
    for (int c = 0; c < 4; ++c) {
      int g = c * 256 + t;
      int row = g >> 3, kc = g & 7;
      const f4v* src = (const f4v*)(X + (size_t)(m0 + row) * Dz + ks * 32 + kc * 4);
      als[row * 9 + (kc ^ (row & 7))] = *src;
    }
    // stage B (copy pre-packed frags)
    size_t b0 = (size_t)(nb * 16 + ks) * 1024;
#pragma unroll
    for (int c = 0; c < 4; ++c) {
      int g = c * 256 + t;
      bls[g] = wp4[b0 + g];
    }
    __syncthreads();
    // A fragments: fp32 -> split bf16 (hi + residual lo)
    s8v ahi[4], alo[4];
#pragma unroll
    for (int mf = 0; mf < 4; ++mf) {
      int row = wm * 64 + mf * 16 + r16;
      f4v a0 = als[row * 9 + ((2 * kg) ^ (row & 7))];
      f4v a1 = als[row * 9 + ((2 * kg + 1) ^ (row & 7))];
      s8v h8, l8;
#pragma unroll
      for (int j = 0; j < 4; ++j) {
        unsigned short hh, ll;
        splitbf(a0[j], hh, ll);
        h8[j] = (short)hh; l8[j] = (short)ll;
        splitbf(a1[j], hh, ll);
        h8[j + 4] = (short)hh; l8[j + 4] = (short)ll;
      }
      ahi[mf] = h8; alo[mf] = l8;
    }
#pragma unroll
    for (int nf = 0; nf < 4; ++nf) {
      int colL = wn * 64 + nf * 16 + r16;
      s8v bhi = *(const s8v*)&bls[0 * 512 + colL * 4 + kg];
      s8v blo = *(const s8v*)&bls[1 * 512 + colL * 4 + kg];
#pragma unroll
      for (int mf = 0; mf < 4; ++mf) {
        acc[mf][nf] = __builtin_amdgcn_mfma_f32_16x16x32_bf16(ahi[mf], bhi, acc[mf][nf], 0, 0, 0);
        acc[mf][nf] = __builtin_amdgcn_mfma_f32_16x16x32_bf16(ahi[mf], blo, acc[mf][nf], 0, 0, 0);
        acc[mf][nf] = __builtin_amdgcn_mfma_f32_16x16x32_bf16(alo[mf], bhi, acc[mf][nf], 0, 0, 0);
      }
    }
  }
  // epilogue: + bias, store fp32 (D: col = lane&15, row = (lane>>4)*4 + r)
#pragma unroll
  for (int nf = 0; nf < 4; ++nf) {
    int col = nb * 128 + wn * 64 + nf * 16 + r16;
    float bz = bias[col];
#pragma unroll
    for (int mf = 0; mf < 4; ++mf) {
      int rowb = m0 + wm * 64 + mf * 16 + kg * 4;
#pragma unroll
      for (int r = 0; r < 4; ++r) {
        out[(size_t)(rowb + r) * Hz + col] = acc[mf][nf][r] + bz;
      }
    }
  }
}

// ---------------- phase 2: persistent recurrence ----------------
// grid 256 (= #CUs, 1 block/CU capacity => all co-resident): group g = bid&7, w = bid>>3
// 4 waves: wn = wave&1 (16-col N-tile), wk = wave>>1 (K-half of 1024)
// R frags resident in VGPRs: rhi/rlo[16] (s8v each)
// h exchanged via hp_hi/hp_lo: [par(2)][b(64)][kk(512)] uint32 (bf16 pair along k)
__launch_bounds__(256, 1)
__global__ void rnn_kernel(const float* __restrict__ h0, const float* __restrict__ R,
                           float* __restrict__ out,
                           unsigned int* __restrict__ hp_hi, unsigned int* __restrict__ hp_lo,
                           unsigned int* __restrict__ cnt) {
  __shared__ f4v red[2][64];
  const int bid = blockIdx.x;
  const int g = bid & 7, w = bid >> 3;
  const int t = threadIdx.x, lane = t & 63, wv = t >> 6;
  const int wn = wv & 1, wk = wv >> 1;
  const int n0 = w * 32;
  const int c16 = lane & 15, kg = lane >> 4;
  const int colG = n0 + wn * 16 + c16;
  const int rquad = kg;                    // output row quad (rows rquad*4+r); valid if <2
  const int brow = g * 8 + (lane & 7);     // A row (rows 8..15 duplicate 0..7, discarded)

  // ---- load R fragments once (persistent) ----
  s8v rhi[16], rlo[16];
#pragma unroll
  for (int s = 0; s < 16; ++s) {
    int kb = wk * 512 + s * 32 + kg * 8;
    s8v h8, l8;
#pragma unroll
    for (int j = 0; j < 8; ++j) {
      unsigned short hh, ll;
      splitbf(R[(size_t)(kb + j) * Hz + colG], hh, ll);
      h8[j] = (short)hh; l8[j] = (short)ll;
    }
    rhi[s] = h8; rlo[s] = l8;
  }

  // ---- prefetch xw[t=0] ----
  float xwv[4] = {0.f, 0.f, 0.f, 0.f};
  const bool wlive = (rquad < 2);
  if (wk == 0 && wlive) {
#pragma unroll
    for (int r = 0; r < 4; ++r)
      xwv[r] = out[((size_t)(g * 8 + rquad * 4 + r) * Tz + 0) * Hz + colG];
  }

  // ---- publish h0 into parity-1 buffer ----
  {
    int b = t >> 5, cl = t & 31;
    unsigned short hh, ll;
    splitbf(h0[(size_t)(g * 8 + b) * Hz + n0 + cl], hh, ll);
    unsigned hu = hh, lu = ll;
    unsigned hn = (unsigned)__shfl_xor((int)hu, 1);
    unsigned ln = (unsigned)__shfl_xor((int)lu, 1);
    if ((t & 1) == 0) {
      size_t idx = (size_t)32768 + (size_t)(g * 8 + b) * 512 + ((n0 + cl) >> 1);
      hp_hi[idx] = hu | (hn << 16);
      hp_lo[idx] = lu | (ln << 16);
    }
  }
  __syncthreads();
  unsigned tgt = 32;
  if (t == 0) {
    __threadfence();                       // release: drain + L2 writeback (cross-XCD)
    atomicAdd(&cnt[g * 16], 1u);
    int guard = 0;
    while (__hip_atomic_load(&cnt[g * 16], __ATOMIC_RELAXED, __HIP_MEMORY_SCOPE_AGENT) < tgt &&
           guard < (1 << 20)) { __builtin_amdgcn_s_sleep(2); ++guard; }
    __threadfence();                       // acquire: invalidate stale lines
  }
  __syncthreads();

  for (int tt = 0; tt < Tz; ++tt) {
    const unsigned* HH = hp_hi + ((tt + 1) & 1) * 32768;
    const unsigned* HL = hp_lo + ((tt + 1) & 1) * 32768;
    f4v acc = f4v{0.f, 0.f, 0.f, 0.f};
#pragma unroll
    for (int s = 0; s < 16; ++s) {
      int kkb = wk * 256 + s * 16 + kg * 4;
      s8v ahi = *(const s8v*)(HH + (size_t)brow * 512 + kkb);
      s8v alo = *(const s8v*)(HL + (size_t)brow * 512 + kkb);
      acc = __builtin_amdgcn_mfma_f32_16x16x32_bf16(ahi, rhi[s], acc, 0, 0, 0);
      acc = __builtin_amdgcn_mfma_f32_16x16x32_bf16(ahi, rlo[s], acc, 0, 0, 0);
      acc = __builtin_amdgcn_mfma_f32_16x16x32_bf16(alo, rhi[s], acc, 0, 0, 0);
    }
    if (wk == 1) red[wn][lane] = acc;
    __syncthreads();
    if (wk == 0) {
      f4v o = red[wn][lane];
      acc = acc + o;
      float hv[4];
#pragma unroll
      for (int r = 0; r < 4; ++r) hv[r] = tanhf(acc[r] + xwv[r]);
      if (wlive) {
#pragma unroll
        for (int r = 0; r < 4; ++r)
          out[((size_t)(g * 8 + rquad * 4 + r) * Tz + tt) * Hz + colG] = hv[r];
      }
      unsigned* DH = hp_hi + (tt & 1) * 32768;
      unsigned* DL = hp_lo + (tt & 1) * 32768;
#pragma unroll
      for (int r = 0; r < 4; ++r) {
        unsigned short hh, ll;
        splitbf(hv[r], hh, ll);
        unsigned hu = hh, lu = ll;
        unsigned hn = (unsigned)__shfl_xor((int)hu, 1);
        unsigned ln = (unsigned)__shfl_xor((int)lu, 1);
        if (wlive && ((lane & 1) == 0)) {
          size_t idx = (size_t)(g * 8 + rquad * 4 + r) * 512 + (colG >> 1);
          DH[idx] = hu | (hn << 16);
          DL[idx] = lu | (ln << 16);
        }
      }
      if (wlive && tt + 1 < Tz) {          // prefetch next xw before the barrier
#pragma unroll
        for (int r = 0; r < 4; ++r)
          xwv[r] = out[((size_t)(g * 8 + rquad * 4 + r) * Tz + (tt + 1)) * Hz + colG];
      }
    }
    if (tt + 1 < Tz) {
      __syncthreads();                     // drains all waves' stores (vmcnt 0 at barrier)
      tgt += 32;
      if (t == 0) {
        __threadfence();
        atomicAdd(&cnt[g * 16], 1u);
        int guard = 0;
        while (__hip_atomic_load(&cnt[g * 16], __ATOMIC_RELAXED, __HIP_MEMORY_SCOPE_AGENT) < tgt &&
               guard < (1 << 20)) { __builtin_amdgcn_s_sleep(2); ++guard; }
        __threadfence();
      }
      __syncthreads();
    }
  }
}

extern "C" void kernel_launch(void* const* d_in, const int* in_sizes, int n_in,
                              void* d_out, int out_size, void* d_ws, size_t ws_size,
                              hipStream_t stream) {
  (void)in_sizes; (void)n_in; (void)out_size; (void)ws_size;
  const float* X  = (const float*)d_in[0];
  const float* h0 = (const float*)d_in[1];
  const float* W  = (const float*)d_in[2];
  const float* R  = (const float*)d_in[3];
  const float* bs = (const float*)d_in[4];
  float* out = (float*)d_out;
  uint8_t* ws = (uint8_t*)d_ws;
  unsigned* wp    = (unsigned*)(ws);                 // 2 MB packed W
  unsigned* hp_hi = (unsigned*)(ws + 0x200000);      // 256 KB
  unsigned* hp_lo = (unsigned*)(ws + 0x240000);      // 256 KB
  unsigned* cnt   = (unsigned*)(ws + 0x280000);      // barrier counters

  hipMemsetAsync(cnt, 0, 1024, stream);
  hipLaunchKernelGGL(wpack_kernel, dim3(128), dim3(256), 0, stream, W, wp);
  hipLaunchKernelGGL(xw_kernel, dim3(2048), dim3(256), 0, stream, X, wp, bs, out);
  hipLaunchKernelGGL(rnn_kernel, dim3(256), dim3(256), 0, stream,
                     h0, R, out, hp_hi, hp_lo, cnt);
}

// Round 4
// 4975.402 us; speedup vs baseline: 1.7200x; 1.7200x over previous
//
#include <hip/hip_runtime.h>
#include <hip/hip_bf16.h>
#include <cstdint>
#include <cstddef>

// SRNN: out = scan(h = tanh(xW_t + h@R)),  B=64 T=512 D_IN=512 H=1024
// phase1 GEMM xW+b -> d_out (fp32, in-place buffer for the scan), split-bf16 both operands;
// phase2 persistent kernel (grid=256=#CUs -> co-resident by capacity),
// R resident in VGPRs (split bf16 hi/lo), per-group (8 groups x 32 WGs) atomic barrier per step.
// h exchange: relaxed agent-scope atomics (sc1 path, coherent at IF$) -- NO __threadfence
// (device fences lower to whole-L2 wbl2/inv on gfx950; they were 16.5us/step in round 3).

#define Bz 64
#define Tz 512
#define Dz 512
#define Hz 1024

typedef __attribute__((ext_vector_type(8))) short s8v;      // 8 bf16 (4 VGPR) MFMA frag
typedef __attribute__((ext_vector_type(4))) float f4v;      // MFMA acc
typedef __attribute__((ext_vector_type(4))) unsigned int u4v;
typedef __attribute__((ext_vector_type(2))) unsigned long long ull2;

union cv16u { ull2 u; s8v s; };

__device__ __forceinline__ unsigned short f2bf(float f) {
  unsigned u = __float_as_uint(f);
  u += 0x7FFFu + ((u >> 16) & 1u);          // RNE
  return (unsigned short)(u >> 16);
}
__device__ __forceinline__ float bf2f(unsigned short h) {
  return __uint_as_float(((unsigned)h) << 16);
}
__device__ __forceinline__ void splitbf(float v, unsigned short& hi, unsigned short& lo) {
  hi = f2bf(v);
  lo = f2bf(v - bf2f(hi));
}

// ---------------- phase 0: pack W -> bf16 hi/lo in MFMA fragment order ----------------
__global__ void wpack_kernel(const float* __restrict__ W, unsigned int* __restrict__ wp) {
  __shared__ float wl[32 * 128];
  const int nb = blockIdx.x >> 4, s = blockIdx.x & 15;
  const int t = threadIdx.x;
#pragma unroll
  for (int i = 0; i < 16; ++i) {
    int idx = i * 256 + t;
    int kr = idx >> 7, nc = idx & 127;
    wl[idx] = W[(size_t)(s * 32 + kr) * Hz + nb * 128 + nc];
  }
  __syncthreads();
#pragma unroll
  for (int i = 0; i < 16; ++i) {
    int u = i * 256 + t;
    int jj = u & 3, kg = (u >> 2) & 3, colL = (u >> 4) & 127, mat = u >> 11;
    int k0 = kg * 8 + jj * 2;
    unsigned short h0_, l0_, h1_, l1_;
    splitbf(wl[k0 * 128 + colL], h0_, l0_);
    splitbf(wl[(k0 + 1) * 128 + colL], h1_, l1_);
    unsigned lo32 = mat ? (unsigned)l0_ : (unsigned)h0_;
    unsigned hi32 = mat ? (unsigned)l1_ : (unsigned)h1_;
    wp[(size_t)((nb * 16 + s) * 2 + mat) * 2048 + (colL * 4 + kg) * 4 + jj] =
        lo32 | (hi32 << 16);
  }
}

// ---------------- phase 1: out = x@W + b (fp32 out), both operands split bf16 ----------------
__launch_bounds__(256, 1)
__global__ void xw_kernel(const float* __restrict__ X, const unsigned int* __restrict__ wp,
                          const float* __restrict__ bias, float* __restrict__ out) {
  __shared__ f4v als[128 * 9];   // A tile fp32, 9-granule row stride + XOR swizzle (bank-safe)
  __shared__ u4v bls[1024];      // B tile, pre-packed bf16 hi/lo frags
  const int bid = blockIdx.x;
  const int mb = bid >> 3, nb = bid & 7;
  const int t = threadIdx.x;
  const int lane = t & 63, wv = t >> 6;
  const int wm = wv >> 1, wn = wv & 1;
  const int r16 = lane & 15, kg = lane >> 4;
  const int m0 = mb * 128;

  f4v acc[4][4];
#pragma unroll
  for (int i = 0; i < 4; ++i)
#pragma unroll
    for (int j = 0; j < 4; ++j) acc[i][j] = f4v{0.f, 0.f, 0.f, 0.f};

  const u4v* wp4 = (const u4v*)wp;

  for (int ks = 0; ks < 16; ++ks) {
    __syncthreads();
#pragma unroll
    for (int c = 0; c < 4; ++c) {
      int g = c * 256 + t;
      int row = g >> 3, kc = g & 7;
      const f4v* src = (const f4v*)(X + (size_t)(m0 + row) * Dz + ks * 32 + kc * 4);
      als[row * 9 + (kc ^ (row & 7))] = *src;
    }
    size_t b0 = (size_t)(nb * 16 + ks) * 1024;
#pragma unroll
    for (int c = 0; c < 4; ++c) {
      int g = c * 256 + t;
      bls[g] = wp4[b0 + g];
    }
    __syncthreads();
    s8v ahi[4], alo[4];
#pragma unroll
    for (int mf = 0; mf < 4; ++mf) {
      int row = wm * 64 + mf * 16 + r16;
      f4v a0 = als[row * 9 + ((2 * kg) ^ (row & 7))];
      f4v a1 = als[row * 9 + ((2 * kg + 1) ^ (row & 7))];
      s8v h8, l8;
#pragma unroll
      for (int j = 0; j < 4; ++j) {
        unsigned short hh, ll;
        splitbf(a0[j], hh, ll);
        h8[j] = (short)hh; l8[j] = (short)ll;
        splitbf(a1[j], hh, ll);
        h8[j + 4] = (short)hh; l8[j + 4] = (short)ll;
      }
      ahi[mf] = h8; alo[mf] = l8;
    }
#pragma unroll
    for (int nf = 0; nf < 4; ++nf) {
      int colL = wn * 64 + nf * 16 + r16;
      s8v bhi = *(const s8v*)&bls[0 * 512 + colL * 4 + kg];
      s8v blo = *(const s8v*)&bls[1 * 512 + colL * 4 + kg];
#pragma unroll
      for (int mf = 0; mf < 4; ++mf) {
        acc[mf][nf] = __builtin_amdgcn_mfma_f32_16x16x32_bf16(ahi[mf], bhi, acc[mf][nf], 0, 0, 0);
        acc[mf][nf] = __builtin_amdgcn_mfma_f32_16x16x32_bf16(ahi[mf], blo, acc[mf][nf], 0, 0, 0);
        acc[mf][nf] = __builtin_amdgcn_mfma_f32_16x16x32_bf16(alo[mf], bhi, acc[mf][nf], 0, 0, 0);
      }
    }
  }
#pragma unroll
  for (int nf = 0; nf < 4; ++nf) {
    int col = nb * 128 + wn * 64 + nf * 16 + r16;
    float bz = bias[col];
#pragma unroll
    for (int mf = 0; mf < 4; ++mf) {
      int rowb = m0 + wm * 64 + mf * 16 + kg * 4;
#pragma unroll
      for (int r = 0; r < 4; ++r) {
        out[(size_t)(rowb + r) * Hz + col] = acc[mf][nf][r] + bz;
      }
    }
  }
}

// ---------------- phase 2: persistent recurrence ----------------
// grid 256: group g = bid&7, w = bid>>3 (cols 32w..32w+32)
// 4 waves: wn = wave&1 (16-col N-tile), wk = wave>>1 (K-half of 1024)
// h exchanged via hp_hi/hp_lo: [par(2)][b(64)][kk(512)] uint32 (bf16 pair along k),
// published with relaxed agent atomics (coherent, no fences).
__launch_bounds__(256, 1)
__global__ void rnn_kernel(const float* __restrict__ h0, const float* __restrict__ R,
                           float* __restrict__ out,
                           unsigned int* __restrict__ hp_hi, unsigned int* __restrict__ hp_lo,
                           unsigned int* __restrict__ cnt) {
  __shared__ f4v red[2][64];
  const int bid = blockIdx.x;
  const int g = bid & 7, w = bid >> 3;
  const int t = threadIdx.x, lane = t & 63, wv = t >> 6;
  const int wn = wv & 1, wk = wv >> 1;
  const int n0 = w * 32;
  const int c16 = lane & 15, kg = lane >> 4;
  const int colG = n0 + wn * 16 + c16;
  const int rquad = kg;                    // output row quad; valid if <2
  const int brow = g * 8 + (lane & 7);     // A row (rows 8..15 duplicate 0..7, discarded)

  // ---- load R fragments once (persistent) ----
  s8v rhi[16], rlo[16];
#pragma unroll
  for (int s = 0; s < 16; ++s) {
    int kb = wk * 512 + s * 32 + kg * 8;
    s8v h8, l8;
#pragma unroll
    for (int j = 0; j < 8; ++j) {
      unsigned short hh, ll;
      splitbf(R[(size_t)(kb + j) * Hz + colG], hh, ll);
      h8[j] = (short)hh; l8[j] = (short)ll;
    }
    rhi[s] = h8; rlo[s] = l8;
  }

  // ---- prefetch xw[t=0] (owner-private slots of out: plain cached loads ok) ----
  float xwv[4] = {0.f, 0.f, 0.f, 0.f};
  const bool wlive = (rquad < 2);
  if (wk == 0 && wlive) {
#pragma unroll
    for (int r = 0; r < 4; ++r)
      xwv[r] = out[((size_t)(g * 8 + rquad * 4 + r) * Tz + 0) * Hz + colG];
  }

  // ---- publish h0 into parity-1 buffer (coherent stores) ----
  {
    int b = t >> 5, cl = t & 31;
    unsigned short hh, ll;
    splitbf(h0[(size_t)(g * 8 + b) * Hz + n0 + cl], hh, ll);
    unsigned hu = hh, lu = ll;
    unsigned hn = (unsigned)__shfl_xor((int)hu, 1);
    unsigned ln = (unsigned)__shfl_xor((int)lu, 1);
    if ((t & 1) == 0) {
      size_t idx = (size_t)32768 + (size_t)(g * 8 + b) * 512 + ((n0 + cl) >> 1);
      __hip_atomic_store(&hp_hi[idx], hu | (hn << 16), __ATOMIC_RELAXED, __HIP_MEMORY_SCOPE_AGENT);
      __hip_atomic_store(&hp_lo[idx], lu | (ln << 16), __ATOMIC_RELAXED, __HIP_MEMORY_SCOPE_AGENT);
    }
  }
  __syncthreads();                         // drains all waves' stores (vmcnt 0 at barrier)
  unsigned tgt = 32;
  if (t == 0) {
    atomicAdd(&cnt[g * 16], 1u);           // device-scope by default (m20)
    int guard = 0;
    while (__hip_atomic_load(&cnt[g * 16], __ATOMIC_RELAXED, __HIP_MEMORY_SCOPE_AGENT) < tgt &&
           guard < (1 << 20)) { __builtin_amdgcn_s_sleep(1); ++guard; }
  }
  __syncthreads();

  for (int tt = 0; tt < Tz; ++tt) {
    const unsigned* HH = hp_hi + ((tt + 1) & 1) * 32768;
    const unsigned* HL = hp_lo + ((tt + 1) & 1) * 32768;

    // ---- load phase: ALL h fragments first (pipelined coherent 64b loads) ----
    s8v ahv[16], alv[16];
#pragma unroll
    for (int s = 0; s < 16; ++s) {
      int kkb = wk * 256 + s * 16 + kg * 4;
      const unsigned long long* ph =
          (const unsigned long long*)(HH + (size_t)brow * 512 + kkb);
      const unsigned long long* pl =
          (const unsigned long long*)(HL + (size_t)brow * 512 + kkb);
      cv16u vh, vl;
      vh.u[0] = __hip_atomic_load(ph + 0, __ATOMIC_RELAXED, __HIP_MEMORY_SCOPE_AGENT);
      vh.u[1] = __hip_atomic_load(ph + 1, __ATOMIC_RELAXED, __HIP_MEMORY_SCOPE_AGENT);
      vl.u[0] = __hip_atomic_load(pl + 0, __ATOMIC_RELAXED, __HIP_MEMORY_SCOPE_AGENT);
      vl.u[1] = __hip_atomic_load(pl + 1, __ATOMIC_RELAXED, __HIP_MEMORY_SCOPE_AGENT);
      ahv[s] = vh.s; alv[s] = vl.s;
    }

    // ---- MFMA phase ----
    f4v acc = f4v{0.f, 0.f, 0.f, 0.f};
#pragma unroll
    for (int s = 0; s < 16; ++s) {
      acc = __builtin_amdgcn_mfma_f32_16x16x32_bf16(ahv[s], rhi[s], acc, 0, 0, 0);
      acc = __builtin_amdgcn_mfma_f32_16x16x32_bf16(ahv[s], rlo[s], acc, 0, 0, 0);
      acc = __builtin_amdgcn_mfma_f32_16x16x32_bf16(alv[s], rhi[s], acc, 0, 0, 0);
    }
    if (wk == 1) red[wn][lane] = acc;
    __syncthreads();
    if (wk == 0) {
      f4v o = red[wn][lane];
      acc = acc + o;
      float hv[4];
#pragma unroll
      for (int r = 0; r < 4; ++r) hv[r] = tanhf(acc[r] + xwv[r]);
      if (wlive) {
#pragma unroll
        for (int r = 0; r < 4; ++r)
          out[((size_t)(g * 8 + rquad * 4 + r) * Tz + tt) * Hz + colG] = hv[r];
      }
      unsigned* DH = hp_hi + (tt & 1) * 32768;
      unsigned* DL = hp_lo + (tt & 1) * 32768;
#pragma unroll
      for (int r = 0; r < 4; ++r) {
        unsigned short hh, ll;
        splitbf(hv[r], hh, ll);
        unsigned hu = hh, lu = ll;
        unsigned hn = (unsigned)__shfl_xor((int)hu, 1);
        unsigned ln = (unsigned)__shfl_xor((int)lu, 1);
        if (wlive && ((lane & 1) == 0)) {
          size_t idx = (size_t)(g * 8 + rquad * 4 + r) * 512 + (colG >> 1);
          __hip_atomic_store(&DH[idx], hu | (hn << 16), __ATOMIC_RELAXED, __HIP_MEMORY_SCOPE_AGENT);
          __hip_atomic_store(&DL[idx], lu | (ln << 16), __ATOMIC_RELAXED, __HIP_MEMORY_SCOPE_AGENT);
        }
      }
      if (wlive && tt + 1 < Tz) {          // prefetch next xw before the barrier
#pragma unroll
        for (int r = 0; r < 4; ++r)
          xwv[r] = out[((size_t)(g * 8 + rquad * 4 + r) * Tz + (tt + 1)) * Hz + colG];
      }
    }
    if (tt + 1 < Tz) {
      __syncthreads();                     // drains all waves' coherent stores
      tgt += 32;
      if (t == 0) {
        atomicAdd(&cnt[g * 16], 1u);
        int guard = 0;
        while (__hip_atomic_load(&cnt[g * 16], __ATOMIC_RELAXED, __HIP_MEMORY_SCOPE_AGENT) < tgt &&
               guard < (1 << 20)) { __builtin_amdgcn_s_sleep(1); ++guard; }
      }
      __syncthreads();
    }
  }
}

extern "C" void kernel_launch(void* const* d_in, const int* in_sizes, int n_in,
                              void* d_out, int out_size, void* d_ws, size_t ws_size,
                              hipStream_t stream) {
  (void)in_sizes; (void)n_in; (void)out_size; (void)ws_size;
  const float* X  = (const float*)d_in[0];
  const float* h0 = (const float*)d_in[1];
  const float* W  = (const float*)d_in[2];
  const float* R  = (const float*)d_in[3];
  const float* bs = (const float*)d_in[4];
  float* out = (float*)d_out;
  uint8_t* ws = (uint8_t*)d_ws;
  unsigned* wp    = (unsigned*)(ws);                 // 2 MB packed W
  unsigned* hp_hi = (unsigned*)(ws + 0x200000);      // 256 KB
  unsigned* hp_lo = (unsigned*)(ws + 0x240000);      // 256 KB
  unsigned* cnt   = (unsigned*)(ws + 0x280000);      // barrier counters

  hipMemsetAsync(cnt, 0, 1024, stream);
  hipLaunchKernelGGL(wpack_kernel, dim3(128), dim3(256), 0, stream, W, wp);
  hipLaunchKernelGGL(xw_kernel, dim3(2048), dim3(256), 0, stream, X, wp, bs, out);
  hipLaunchKernelGGL(rnn_kernel, dim3(256), dim3(256), 0, stream,
                     h0, R, out, hp_hi, hp_lo, cnt);
}

// Round 8
// 4974.699 us; speedup vs baseline: 1.7202x; 1.0001x over previous
//
#include <hip/hip_runtime.h>
#include <hip/hip_bf16.h>
#include <cstdint>
#include <cstddef>

// SRNN: out = scan(h = tanh(xW_t + h@R)),  B=64 T=512 D_IN=512 H=1024
// phase1 GEMM xW+b -> d_out (fp32, in-place buffer for the scan), split-bf16 both operands;
// phase2 persistent kernel (grid=256=#CUs -> co-resident by capacity),
// R resident in VGPRs (split bf16 hi/lo), 8 groups x 32 WGs.
// h exchange: relaxed agent-scope atomics (round-4 proven).
// Barrier (round 5): parallel per-WG flag stores + per-lane flag poll
// (replaces 32 serialized atomicAdd RMWs -- that was ~5-7us of the 9us step).

#define Bz 64
#define Tz 512
#define Dz 512
#define Hz 1024

typedef __attribute__((ext_vector_type(8))) short s8v;      // 8 bf16 (4 VGPR) MFMA frag
typedef __attribute__((ext_vector_type(4))) float f4v;      // MFMA acc
typedef __attribute__((ext_vector_type(4))) unsigned int u4v;
typedef __attribute__((ext_vector_type(2))) unsigned long long ull2;

union cv16u { ull2 u; s8v s; };

__device__ __forceinline__ unsigned short f2bf(float f) {
  unsigned u = __float_as_uint(f);
  u += 0x7FFFu + ((u >> 16) & 1u);          // RNE
  return (unsigned short)(u >> 16);
}
__device__ __forceinline__ float bf2f(unsigned short h) {
  return __uint_as_float(((unsigned)h) << 16);
}
__device__ __forceinline__ void splitbf(float v, unsigned short& hi, unsigned short& lo) {
  hi = f2bf(v);
  lo = f2bf(v - bf2f(hi));
}

// ---------------- phase 0: pack W -> bf16 hi/lo in MFMA fragment order ----------------
__global__ void wpack_kernel(const float* __restrict__ W, unsigned int* __restrict__ wp) {
  __shared__ float wl[32 * 128];
  const int nb = blockIdx.x >> 4, s = blockIdx.x & 15;
  const int t = threadIdx.x;
#pragma unroll
  for (int i = 0; i < 16; ++i) {
    int idx = i * 256 + t;
    int kr = idx >> 7, nc = idx & 127;
    wl[idx] = W[(size_t)(s * 32 + kr) * Hz + nb * 128 + nc];
  }
  __syncthreads();
#pragma unroll
  for (int i = 0; i < 16; ++i) {
    int u = i * 256 + t;
    int jj = u & 3, kg = (u >> 2) & 3, colL = (u >> 4) & 127, mat = u >> 11;
    int k0 = kg * 8 + jj * 2;
    unsigned short h0_, l0_, h1_, l1_;
    splitbf(wl[k0 * 128 + colL], h0_, l0_);
    splitbf(wl[(k0 + 1) * 128 + colL], h1_, l1_);
    unsigned lo32 = mat ? (unsigned)l0_ : (unsigned)h0_;
    unsigned hi32 = mat ? (unsigned)l1_ : (unsigned)h1_;
    wp[(size_t)((nb * 16 + s) * 2 + mat) * 2048 + (colL * 4 + kg) * 4 + jj] =
        lo32 | (hi32 << 16);
  }
}

// ---------------- phase 1: out = x@W + b (fp32 out), both operands split bf16 ----------------
__launch_bounds__(256, 1)
__global__ void xw_kernel(const float* __restrict__ X, const unsigned int* __restrict__ wp,
                          const float* __restrict__ bias, float* __restrict__ out) {
  __shared__ f4v als[128 * 9];   // A tile fp32, 9-granule row stride + XOR swizzle (bank-safe)
  __shared__ u4v bls[1024];      // B tile, pre-packed bf16 hi/lo frags
  const int bid = blockIdx.x;
  const int mb = bid >> 3, nb = bid & 7;
  const int t = threadIdx.x;
  const int lane = t & 63, wv = t >> 6;
  const int wm = wv >> 1, wn = wv & 1;
  const int r16 = lane & 15, kg = lane >> 4;
  const int m0 = mb * 128;

  f4v acc[4][4];
#pragma unroll
  for (int i = 0; i < 4; ++i)
#pragma unroll
    for (int j = 0; j < 4; ++j) acc[i][j] = f4v{0.f, 0.f, 0.f, 0.f};

  const u4v* wp4 = (const u4v*)wp;

  for (int ks = 0; ks < 16; ++ks) {
    __syncthreads();
#pragma unroll
    for (int c = 0; c < 4; ++c) {
      int g = c * 256 + t;
      int row = g >> 3, kc = g & 7;
      const f4v* src = (const f4v*)(X + (size_t)(m0 + row) * Dz + ks * 32 + kc * 4);
      als[row * 9 + (kc ^ (row & 7))] = *src;
    }
    size_t b0 = (size_t)(nb * 16 + ks) * 1024;
#pragma unroll
    for (int c = 0; c < 4; ++c) {
      int g = c * 256 + t;
      bls[g] = wp4[b0 + g];
    }
    __syncthreads();
    s8v ahi[4], alo[4];
#pragma unroll
    for (int mf = 0; mf < 4; ++mf) {
      int row = wm * 64 + mf * 16 + r16;
      f4v a0 = als[row * 9 + ((2 * kg) ^ (row & 7))];
      f4v a1 = als[row * 9 + ((2 * kg + 1) ^ (row & 7))];
      s8v h8, l8;
#pragma unroll
      for (int j = 0; j < 4; ++j) {
        unsigned short hh, ll;
        splitbf(a0[j], hh, ll);
        h8[j] = (short)hh; l8[j] = (short)ll;
        splitbf(a1[j], hh, ll);
        h8[j + 4] = (short)hh; l8[j + 4] = (short)ll;
      }
      ahi[mf] = h8; alo[mf] = l8;
    }
#pragma unroll
    for (int nf = 0; nf < 4; ++nf) {
      int colL = wn * 64 + nf * 16 + r16;
      s8v bhi = *(const s8v*)&bls[0 * 512 + colL * 4 + kg];
      s8v blo = *(const s8v*)&bls[1 * 512 + colL * 4 + kg];
#pragma unroll
      for (int mf = 0; mf < 4; ++mf) {
        acc[mf][nf] = __builtin_amdgcn_mfma_f32_16x16x32_bf16(ahi[mf], bhi, acc[mf][nf], 0, 0, 0);
        acc[mf][nf] = __builtin_amdgcn_mfma_f32_16x16x32_bf16(ahi[mf], blo, acc[mf][nf], 0, 0, 0);
        acc[mf][nf] = __builtin_amdgcn_mfma_f32_16x16x32_bf16(alo[mf], bhi, acc[mf][nf], 0, 0, 0);
      }
    }
  }
#pragma unroll
  for (int nf = 0; nf < 4; ++nf) {
    int col = nb * 128 + wn * 64 + nf * 16 + r16;
    float bz = bias[col];
#pragma unroll
    for (int mf = 0; mf < 4; ++mf) {
      int rowb = m0 + wm * 64 + mf * 16 + kg * 4;
#pragma unroll
      for (int r = 0; r < 4; ++r) {
        out[(size_t)(rowb + r) * Hz + col] = acc[mf][nf][r] + bz;
      }
    }
  }
}

// ---------------- phase 2: persistent recurrence ----------------
// grid 256: group g = bid&7, w = bid>>3 (cols 32w..32w+32)
// 4 waves: wn = wave&1 (16-col N-tile), wk = wave>>1 (K-half of 1024)
// Barrier: flag[g*32+w] = step (parallel stores); wave0 lane polls flag[g*32+(lane&31)].
__launch_bounds__(256, 1)
__global__ void rnn_kernel(const float* __restrict__ h0, const float* __restrict__ R,
                           float* __restrict__ out,
                           unsigned int* __restrict__ hp_hi, unsigned int* __restrict__ hp_lo,
                           unsigned int* __restrict__ flag) {
  __shared__ f4v red[2][64];
  const int bid = blockIdx.x;
  const int g = bid & 7, w = bid >> 3;
  const int t = threadIdx.x, lane = t & 63, wv = t >> 6;
  const int wn = wv & 1, wk = wv >> 1;
  const int n0 = w * 32;
  const int c16 = lane & 15, kg = lane >> 4;
  const int colG = n0 + wn * 16 + c16;
  const int rquad = kg;                    // output row quad; valid if <2
  const int brow = g * 8 + (lane & 7);     // A row (rows 8..15 duplicate 0..7, discarded)

  // ---- load R fragments once (persistent) ----
  s8v rhi[16], rlo[16];
#pragma unroll
  for (int s = 0; s < 16; ++s) {
    int kb = wk * 512 + s * 32 + kg * 8;
    s8v h8, l8;
#pragma unroll
    for (int j = 0; j < 8; ++j) {
      unsigned short hh, ll;
      splitbf(R[(size_t)(kb + j) * Hz + colG], hh, ll);
      h8[j] = (short)hh; l8[j] = (short)ll;
    }
    rhi[s] = h8; rlo[s] = l8;
  }

  // ---- prefetch xw[t=0] (owner-private slots of out: plain cached loads ok) ----
  float xwv[4] = {0.f, 0.f, 0.f, 0.f};
  const bool wlive = (rquad < 2);
  if (wk == 0 && wlive) {
#pragma unroll
    for (int r = 0; r < 4; ++r)
      xwv[r] = out[((size_t)(g * 8 + rquad * 4 + r) * Tz + 0) * Hz + colG];
  }

  // ---- publish h0 into parity-1 buffer (coherent stores) ----
  {
    int b = t >> 5, cl = t & 31;
    unsigned short hh, ll;
    splitbf(h0[(size_t)(g * 8 + b) * Hz + n0 + cl], hh, ll);
    unsigned hu = hh, lu = ll;
    unsigned hn = (unsigned)__shfl_xor((int)hu, 1);
    unsigned ln = (unsigned)__shfl_xor((int)lu, 1);
    if ((t & 1) == 0) {
      size_t idx = (size_t)32768 + (size_t)(g * 8 + b) * 512 + ((n0 + cl) >> 1);
      __hip_atomic_store(&hp_hi[idx], hu | (hn << 16), __ATOMIC_RELAXED, __HIP_MEMORY_SCOPE_AGENT);
      __hip_atomic_store(&hp_lo[idx], lu | (ln << 16), __ATOMIC_RELAXED, __HIP_MEMORY_SCOPE_AGENT);
    }
  }
  __syncthreads();                         // drains all waves' stores (vmcnt 0 at barrier)
  // ---- flag barrier, step 1 ----
  if (t == 0)
    __hip_atomic_store(&flag[g * 32 + w], 1u, __ATOMIC_RELAXED, __HIP_MEMORY_SCOPE_AGENT);
  if (wv == 0) {
    const unsigned* fp = flag + g * 32 + (lane & 31);
    int guard = 0;
    while (guard < (1 << 20)) {
      unsigned v = __hip_atomic_load(fp, __ATOMIC_RELAXED, __HIP_MEMORY_SCOPE_AGENT);
      if (__all(v >= 1u)) break;
      __builtin_amdgcn_s_sleep(1);
      ++guard;
    }
  }
  __syncthreads();

  for (int tt = 0; tt < Tz; ++tt) {
    const unsigned* HH = hp_hi + ((tt + 1) & 1) * 32768;
    const unsigned* HL = hp_lo + ((tt + 1) & 1) * 32768;

    // ---- load phase: ALL h fragments first (pipelined coherent 64b loads) ----
    s8v ahv[16], alv[16];
#pragma unroll
    for (int s = 0; s < 16; ++s) {
      int kkb = wk * 256 + s * 16 + kg * 4;
      const unsigned long long* ph =
          (const unsigned long long*)(HH + (size_t)brow * 512 + kkb);
      const unsigned long long* pl =
          (const unsigned long long*)(HL + (size_t)brow * 512 + kkb);
      cv16u vh, vl;
      vh.u[0] = __hip_atomic_load(ph + 0, __ATOMIC_RELAXED, __HIP_MEMORY_SCOPE_AGENT);
      vh.u[1] = __hip_atomic_load(ph + 1, __ATOMIC_RELAXED, __HIP_MEMORY_SCOPE_AGENT);
      vl.u[0] = __hip_atomic_load(pl + 0, __ATOMIC_RELAXED, __HIP_MEMORY_SCOPE_AGENT);
      vl.u[1] = __hip_atomic_load(pl + 1, __ATOMIC_RELAXED, __HIP_MEMORY_SCOPE_AGENT);
      ahv[s] = vh.s; alv[s] = vl.s;
    }

    // ---- MFMA phase ----
    f4v acc = f4v{0.f, 0.f, 0.f, 0.f};
#pragma unroll
    for (int s = 0; s < 16; ++s) {
      acc = __builtin_amdgcn_mfma_f32_16x16x32_bf16(ahv[s], rhi[s], acc, 0, 0, 0);
      acc = __builtin_amdgcn_mfma_f32_16x16x32_bf16(ahv[s], rlo[s], acc, 0, 0, 0);
      acc = __builtin_amdgcn_mfma_f32_16x16x32_bf16(alv[s], rhi[s], acc, 0, 0, 0);
    }
    if (wk == 1) red[wn][lane] = acc;
    __syncthreads();
    if (wk == 0) {
      f4v o = red[wn][lane];
      acc = acc + o;
      float hv[4];
#pragma unroll
      for (int r = 0; r < 4; ++r) hv[r] = tanhf(acc[r] + xwv[r]);
      if (wlive) {
#pragma unroll
        for (int r = 0; r < 4; ++r)
          out[((size_t)(g * 8 + rquad * 4 + r) * Tz + tt) * Hz + colG] = hv[r];
      }
      unsigned* DH = hp_hi + (tt & 1) * 32768;
      unsigned* DL = hp_lo + (tt & 1) * 32768;
#pragma unroll
      for (int r = 0; r < 4; ++r) {
        unsigned short hh, ll;
        splitbf(hv[r], hh, ll);
        unsigned hu = hh, lu = ll;
        unsigned hn = (unsigned)__shfl_xor((int)hu, 1);
        unsigned ln = (unsigned)__shfl_xor((int)lu, 1);
        if (wlive && ((lane & 1) == 0)) {
          size_t idx = (size_t)(g * 8 + rquad * 4 + r) * 512 + (colG >> 1);
          __hip_atomic_store(&DH[idx], hu | (hn << 16), __ATOMIC_RELAXED, __HIP_MEMORY_SCOPE_AGENT);
          __hip_atomic_store(&DL[idx], lu | (ln << 16), __ATOMIC_RELAXED, __HIP_MEMORY_SCOPE_AGENT);
        }
      }
      if (wlive && tt + 1 < Tz) {          // prefetch next xw before the barrier
#pragma unroll
        for (int r = 0; r < 4; ++r)
          xwv[r] = out[((size_t)(g * 8 + rquad * 4 + r) * Tz + (tt + 1)) * Hz + colG];
      }
    }
    if (tt + 1 < Tz) {
      __syncthreads();                     // drains all waves' coherent stores
      unsigned tgt = (unsigned)(tt + 2);
      if (t == 0)
        __hip_atomic_store(&flag[g * 32 + w], tgt, __ATOMIC_RELAXED, __HIP_MEMORY_SCOPE_AGENT);
      if (wv == 0) {
        const unsigned* fp = flag + g * 32 + (lane & 31);
        int guard = 0;
        while (guard < (1 << 20)) {
          unsigned v = __hip_atomic_load(fp, __ATOMIC_RELAXED, __HIP_MEMORY_SCOPE_AGENT);
          if (__all(v >= tgt)) break;
          __builtin_amdgcn_s_sleep(1);
          ++guard;
        }
      }
      __syncthreads();
    }
  }
}

extern "C" void kernel_launch(void* const* d_in, const int* in_sizes, int n_in,
                              void* d_out, int out_size, void* d_ws, size_t ws_size,
                              hipStream_t stream) {
  (void)in_sizes; (void)n_in; (void)out_size; (void)ws_size;
  const float* X  = (const float*)d_in[0];
  const float* h0 = (const float*)d_in[1];
  const float* W  = (const float*)d_in[2];
  const float* R  = (const float*)d_in[3];
  const float* bs = (const float*)d_in[4];
  float* out = (float*)d_out;
  uint8_t* ws = (uint8_t*)d_ws;
  unsigned* wp    = (unsigned*)(ws);                 // 2 MB packed W
  unsigned* hp_hi = (unsigned*)(ws + 0x200000);      // 256 KB
  unsigned* hp_lo = (unsigned*)(ws + 0x240000);      // 256 KB
  unsigned* flag  = (unsigned*)(ws + 0x280000);      // 256 barrier flags

  hipMemsetAsync(flag, 0, 1024, stream);
  hipLaunchKernelGGL(wpack_kernel, dim3(128), dim3(256), 0, stream, W, wp);
  hipLaunchKernelGGL(xw_kernel, dim3(2048), dim3(256), 0, stream, X, wp, bs, out);
  hipLaunchKernelGGL(rnn_kernel, dim3(256), dim3(256), 0, stream,
                     h0, R, out, hp_hi, hp_lo, flag);
}